// Round 16
// baseline (50.273 us; speedup 1.0000x reference)
//
#include <hip/hip_runtime.h>
#include <math.h>

constexpr int BGR=1024, NN=128, EG=2048, FIN=30, H1=30, H2=50, K1=103, K2=83, FCW=100;
constexpr int NT=256;
constexpr int EPT=EG/NT;          // 8 packed edges/thread
constexpr int EGP=EG+NN*4;        // padded CSR capacity (deg rounded to x4)
constexpr int SA=36;
constexpr int XBSZ=(NN+1)*32;     // 129 rows; row 128 = zero row (pad sentinel 0x80)
constexpr int AGSZ=NN*SA;         // 4608
// AGG-relative scratch (rows >=104 free: dwords 3744..4607)
constexpr int SD0=3744, POL=4200, ZFC=4304;
// FT: [103][51] gated-value buffer for pool scan; aliases SMEM[0..5252]

// row s, feature i -> dword s*32 + (((i>>2)+s)&7)*4 + (i&3)
__device__ __forceinline__ void row_add4(const float* XB, int s, int cq,
                                         float4&a0, float4&a1, float4&a2, float4&a3){
  int b=s<<5, r=s&7;
  float4 v0=*(const float4*)&XB[b+(((cq  +r)&7)<<2)];
  float4 v1=*(const float4*)&XB[b+(((cq+1+r)&7)<<2)];
  float4 v2=*(const float4*)&XB[b+(((cq+2+r)&7)<<2)];
  float4 v3=*(const float4*)&XB[b+(((cq+3+r)&7)<<2)];
  a0.x+=v0.x; a0.y+=v0.y; a0.z+=v0.z; a0.w+=v0.w;
  a1.x+=v1.x; a1.y+=v1.y; a1.z+=v1.z; a1.w+=v1.w;
  a2.x+=v2.x; a2.y+=v2.y; a2.z+=v2.z; a2.w+=v2.w;
  a3.x+=v3.x; a3.y+=v3.y; a3.z+=v3.z; a3.w+=v3.w;
}

__global__ __launch_bounds__(NT,4) void gnn_fused(
    const float* __restrict__ x, const int* __restrict__ ei,
    const float* __restrict__ W1, const float* __restrict__ b1, const float* __restrict__ p1,
    const float* __restrict__ W2, const float* __restrict__ b2, const float* __restrict__ p2,
    const float* __restrict__ fc1W, const float* __restrict__ fc1b,
    const float* __restrict__ fc2W, const float* __restrict__ fc2b,
    float* __restrict__ out)
{
  const int g=blockIdx.x, tid=threadIdx.x, lane=tid&63, wv=tid>>6;
  const int hf=wv&1;                         // wave-uniform feature half
  const int nG=(tid>>7)*64+lane;             // node: waves{0,1}->0..63, {2,3}->64..127
  const int hfu=__builtin_amdgcn_readfirstlane(hf);
  const int cq=hfu<<2;                       // first of this half's 4 chunks

  __shared__ __align__(16) float SMEM[XBSZ+AGSZ];
  float* XB  = SMEM;
  float* AGG = SMEM+XBSZ;
  float* FT  = SMEM;                          // pool buffer, aliases dead XB/AGG-front
  __shared__ unsigned char eord[EGP];
  __shared__ int cur[NN];
  __shared__ short cstart[NN];
  __shared__ __align__(16) float dsc[NN];    // dinv1->score1->dinv2->score2
  __shared__ signed char rmap[NN];
  __shared__ int sh_wtot;

  // ---- packed edges + x preloaded into registers ----
  int epk[EPT];
  {
    const int* srcg=ei+(size_t)g*EG;
    const int* dstg=ei+(size_t)BGR*EG+(size_t)g*EG;
    #pragma unroll
    for(int j=0;j<EPT;j++){ int e=tid+j*NT; epk[j]=(srcg[e]&127)|((dstg[e]&127)<<8); }
  }
  float2 xr[8];
  #pragma unroll
  for(int k=0;k<8;k++){
    int l2=tid+k*NT;
    if(l2<NN*15){
      int n=l2/15, i=(l2-n*15)*2;
      xr[k]=*(const float2*)&x[(size_t)g*NN*FIN+n*FIN+i];
    }
  }
  // ---- init: pads, zero row 128, counters ----
  if(tid<NN){ int o=(tid<<5)+(((7+tid)&7)<<2); XB[o+2]=0.f; XB[o+3]=0.f; cur[tid]=0; }
  if(tid>=NN && tid<NN+32) XB[NN*32+(tid-NN)]=0.f;
  __syncthreads();

  // ================= CSR build 1 (pad4, sentinel row 128) =================
  #pragma unroll
  for(int j=0;j<EPT;j++) atomicAdd(&cur[epk[j]>>8],1);
  __syncthreads();
  {
    int mydeg=(tid<NN)?cur[tid]:0;
    int mydeg4=(mydeg+3)&~3;
    int v=mydeg4;
    #pragma unroll
    for(int off=1;off<64;off<<=1){ int t=__shfl_up(v,off,64); if(lane>=off)v+=t; }
    if(tid==63) sh_wtot=v;
    for(int l=tid;l<EGP/4;l+=NT) ((int*)eord)[l]=0x80808080;   // holes -> zero row
    __syncthreads();
    if(tid<NN){
      int start=v-mydeg4+((tid>=64)?sh_wtot:0);
      cur[tid]=start; cstart[tid]=(short)start;
      dsc[tid]=1.0f/sqrtf((float)mydeg+1.0f);                  // dinv1
    }
  }
  __syncthreads();
  // ---- stage x scaled by dinv1 (from regs) + scatter1 (one phase) ----
  #pragma unroll
  for(int k=0;k<8;k++){
    int l2=tid+k*NT;
    if(l2<NN*15){
      int n=l2/15, i=(l2-n*15)*2;
      float di=dsc[n];
      float2 v=xr[k]; v.x*=di; v.y*=di;
      *(float2*)&XB[(n<<5)+((((i>>2)+n)&7)<<2)+(i&3)]=v;
    }
  }
  #pragma unroll
  for(int j=0;j<EPT;j++){ int p=atomicAdd(&cur[epk[j]>>8],1); eord[p]=(unsigned char)(epk[j]&255); }
  __syncthreads();

  // ================= gather1: pure row-sum, final x dinv1 ====================
  {
    float4 a0={0,0,0,0},a1={0,0,0,0},a2={0,0,0,0},a3={0,0,0,0};
    int e0=cstart[nG], deg=cur[nG]-e0;
    int kend=e0+((deg+3)&~3);
    for(int k=e0;k<kend;k+=4){
      uchar4 ss=*(const uchar4*)&eord[k];
      row_add4(XB,ss.x,cq,a0,a1,a2,a3);
      row_add4(XB,ss.y,cq,a0,a1,a2,a3);
      row_add4(XB,ss.z,cq,a0,a1,a2,a3);
      row_add4(XB,ss.w,cq,a0,a1,a2,a3);
    }
    row_add4(XB,nG,cq,a0,a1,a2,a3);          // self: dinv*(... + x'[n])
    float di=dsc[nG];
    a0.x*=di; a0.y*=di; a0.z*=di; a0.w*=di;
    a1.x*=di; a1.y*=di; a1.z*=di; a1.w*=di;
    a2.x*=di; a2.y*=di; a2.z*=di; a2.w*=di;
    a3.x*=di; a3.y*=di; a3.z*=di; a3.w*=di;
    float* dp=&AGG[nG*SA + (hfu<<4)];        // half0 -> feats 0..15, half1 -> 16..29
    ((float4*)dp)[0]=a0; ((float4*)dp)[1]=a1; ((float4*)dp)[2]=a2;
    if(!hfu) ((float4*)dp)[3]=a3;
    else     *(float2*)(dp+12)=make_float2(a3.x,a3.y);
  }
  __syncthreads();                 // x' dead; agg1 ready

  // ================= mm1: scalar-W (wave-uniform) ============================
  // half0 computes 16 cols (0..15) so the gated write is 4x float4; col 15 is
  // bitwise-identical to half1's former col-15 (same A row, same FMA order).
  // Score dots keep the exact 15/15 split -> scores unchanged.
  float h[16];
  {
    float A[30];
    {
      const float* arow=&AGG[nG*SA];
      float4 t0=((const float4*)arow)[0],t1=((const float4*)arow)[1],t2=((const float4*)arow)[2],
             t3=((const float4*)arow)[3],t4=((const float4*)arow)[4],t5=((const float4*)arow)[5],
             t6=((const float4*)arow)[6];
      float2 t7=*(const float2*)(arow+28);
      A[0]=t0.x;A[1]=t0.y;A[2]=t0.z;A[3]=t0.w; A[4]=t1.x;A[5]=t1.y;A[6]=t1.z;A[7]=t1.w;
      A[8]=t2.x;A[9]=t2.y;A[10]=t2.z;A[11]=t2.w; A[12]=t3.x;A[13]=t3.y;A[14]=t3.z;A[15]=t3.w;
      A[16]=t4.x;A[17]=t4.y;A[18]=t4.z;A[19]=t4.w; A[20]=t5.x;A[21]=t5.y;A[22]=t5.z;A[23]=t5.w;
      A[24]=t6.x;A[25]=t6.y;A[26]=t6.z;A[27]=t6.w; A[28]=t7.x;A[29]=t7.y;
    }
    const int NC = hfu ? 15 : 16;            // wave-uniform
    const float* W1u=W1+hfu*15;
    const float* b1u=b1+hfu*15;
    #pragma unroll
    for(int jo=0;jo<16;jo++) h[jo]=(jo<NC)?b1u[jo]:0.f;
    #pragma unroll
    for(int i=0;i<FIN;i++){
      float ai=A[i];
      #pragma unroll
      for(int jo=0;jo<16;jo++) if(jo<NC) h[jo]=fmaf(ai,W1u[i*H1+jo],h[jo]);
    }
    #pragma unroll
    for(int jo=0;jo<16;jo++) if(jo<NC) h[jo]=fmaxf(h[jo],0.f);
  }

  // ---- pool1 partial score (per half, exact 15/15 split as before) ----
  {
    const float* p1u=p1+hfu*15;
    float d=0.f;
    #pragma unroll
    for(int jo=0;jo<15;jo++) d += h[jo]*p1u[jo];
    AGG[SD0 + hf*128 + nG]=d;
  }
  __syncthreads();
  if(tid<NN){
    float nr=0.f;
    #pragma unroll
    for(int i=0;i<H1;i++){ float pv=p1[i]; nr+=pv*pv; }
    float dt=AGG[SD0+tid]+AGG[SD0+128+tid];
    dsc[tid]=tanhf(dt/sqrtf(nr));            // score1
  }
  __syncthreads();
  if(tid<NN){                                 // rank1: vectorized, same predicate
    float si=dsc[tid]; int r=0;
    #pragma unroll 8
    for(int m4=0;m4<32;m4++){
      float4 v=*(const float4*)&dsc[m4*4];
      int m=m4*4;
      r += (v.x>si)||(v.x==si&&(m  )<tid);
      r += (v.y>si)||(v.y==si&&(m+1)<tid);
      r += (v.z>si)||(v.z==si&&(m+2)<tid);
      r += (v.w>si)||(v.w==si&&(m+3)<tid);
    }
    rmap[tid]=(r<K1)?(signed char)r:(signed char)-1;
  }
  __syncthreads();
  {  // gated compact -> swizzled XB rank rows, float4 writes
    int r=rmap[nG];
    if(r>=0){
      float gv=dsc[nG];
      int b=(r<<5), ro=r&7;
      if(!hfu){
        *(float4*)&XB[b+(((0+ro)&7)<<2)]=make_float4(h[0]*gv,h[1]*gv,h[2]*gv,h[3]*gv);
        *(float4*)&XB[b+(((1+ro)&7)<<2)]=make_float4(h[4]*gv,h[5]*gv,h[6]*gv,h[7]*gv);
        *(float4*)&XB[b+(((2+ro)&7)<<2)]=make_float4(h[8]*gv,h[9]*gv,h[10]*gv,h[11]*gv);
        *(float4*)&XB[b+(((3+ro)&7)<<2)]=make_float4(h[12]*gv,h[13]*gv,h[14]*gv,h[15]*gv);
      } else {
        *(float4*)&XB[b+(((4+ro)&7)<<2)]=make_float4(h[1]*gv,h[2]*gv,h[3]*gv,h[4]*gv);
        *(float4*)&XB[b+(((5+ro)&7)<<2)]=make_float4(h[5]*gv,h[6]*gv,h[7]*gv,h[8]*gv);
        *(float4*)&XB[b+(((6+ro)&7)<<2)]=make_float4(h[9]*gv,h[10]*gv,h[11]*gv,h[12]*gv);
        *(float4*)&XB[b+(((7+ro)&7)<<2)]=make_float4(h[13]*gv,h[14]*gv,0.f,0.f);
      }
    }
  }
  #pragma unroll
  for(int j=0;j<EPT;j++){
    int ns=rmap[epk[j]&255], nd=rmap[epk[j]>>8];
    epk[j]=((ns|nd)<0)? -1 : (ns|(nd<<8));
  }
  if(tid<K1) cur[tid]=0;
  __syncthreads();

  // ================= CSR build 2 (pruned, rank ids) =================
  #pragma unroll
  for(int j=0;j<EPT;j++) if(epk[j]>=0) atomicAdd(&cur[epk[j]>>8],1);
  __syncthreads();
  {
    int mydeg=(tid<K1)?cur[tid]:0;
    int mydeg4=(mydeg+3)&~3;
    int v=mydeg4;
    #pragma unroll
    for(int off=1;off<64;off<<=1){ int t=__shfl_up(v,off,64); if(lane>=off)v+=t; }
    if(tid==63) sh_wtot=v;
    for(int l=tid;l<EGP/4;l+=NT) ((int*)eord)[l]=0x80808080;
    __syncthreads();
    if(tid<K1){
      int start=v-mydeg4+((tid>=64)?sh_wtot:0);
      cur[tid]=start; cstart[tid]=(short)start;
      dsc[tid]=1.0f/sqrtf((float)mydeg+1.0f);            // dinv2 (by rank id)
    }
  }
  __syncthreads();
  // ---- scatter2 + prescale2 fused (disjoint targets) ----
  #pragma unroll
  for(int j=0;j<EPT;j++) if(epk[j]>=0){ int p=atomicAdd(&cur[epk[j]>>8],1); eord[p]=(unsigned char)(epk[j]&255); }
  if(nG<K1){
    float d2=dsc[nG];
    int b=nG<<5, r=nG&7;
    #pragma unroll
    for(int c=0;c<4;c++){
      float4* q=(float4*)&XB[b+((((cq+c)+r)&7)<<2)];
      float4 v=*q;
      v.x*=d2; v.y*=d2; v.z*=d2; v.w*=d2;
      *q=v;
    }
  }
  __syncthreads();

  // ================= gather2: pure row-sum (pruned CSR), final x dinv2 =======
  if(nG<K1){
    float4 a0={0,0,0,0},a1={0,0,0,0},a2={0,0,0,0},a3={0,0,0,0};
    int e0=cstart[nG], deg=cur[nG]-e0;
    int kend=e0+((deg+3)&~3);
    for(int k=e0;k<kend;k+=4){
      uchar4 ss=*(const uchar4*)&eord[k];
      row_add4(XB,ss.x,cq,a0,a1,a2,a3);
      row_add4(XB,ss.y,cq,a0,a1,a2,a3);
      row_add4(XB,ss.z,cq,a0,a1,a2,a3);
      row_add4(XB,ss.w,cq,a0,a1,a2,a3);
    }
    row_add4(XB,nG,cq,a0,a1,a2,a3);
    float d2=dsc[nG];
    a0.x*=d2; a0.y*=d2; a0.z*=d2; a0.w*=d2;
    a1.x*=d2; a1.y*=d2; a1.z*=d2; a1.w*=d2;
    a2.x*=d2; a2.y*=d2; a2.z*=d2; a2.w*=d2;
    a3.x*=d2; a3.y*=d2; a3.z*=d2; a3.w*=d2;
    float* dp=&AGG[nG*SA + (hfu<<4)];
    ((float4*)dp)[0]=a0; ((float4*)dp)[1]=a1; ((float4*)dp)[2]=a2;
    if(!hfu) ((float4*)dp)[3]=a3;
    else     *(float2*)(dp+12)=make_float2(a3.x,a3.y);
  }
  __syncthreads();                 // agg2 ready

  // ================= mm2: scalar-W + pool2 partial ===========================
  float oc[25];
  if(nG<K1){
    float A[30];
    {
      const float* arow=&AGG[nG*SA];
      float4 t0=((const float4*)arow)[0],t1=((const float4*)arow)[1],t2=((const float4*)arow)[2],
             t3=((const float4*)arow)[3],t4=((const float4*)arow)[4],t5=((const float4*)arow)[5],
             t6=((const float4*)arow)[6];
      float2 t7=*(const float2*)(arow+28);
      A[0]=t0.x;A[1]=t0.y;A[2]=t0.z;A[3]=t0.w; A[4]=t1.x;A[5]=t1.y;A[6]=t1.z;A[7]=t1.w;
      A[8]=t2.x;A[9]=t2.y;A[10]=t2.z;A[11]=t2.w; A[12]=t3.x;A[13]=t3.y;A[14]=t3.z;A[15]=t3.w;
      A[16]=t4.x;A[17]=t4.y;A[18]=t4.z;A[19]=t4.w; A[20]=t5.x;A[21]=t5.y;A[22]=t5.z;A[23]=t5.w;
      A[24]=t6.x;A[25]=t6.y;A[26]=t6.z;A[27]=t6.w; A[28]=t7.x;A[29]=t7.y;
    }
    const float* W2u=W2+hfu*25;
    const float* b2u=b2+hfu*25;
    #pragma unroll
    for(int jo=0;jo<25;jo++) oc[jo]=b2u[jo];
    #pragma unroll
    for(int i=0;i<H1;i++){
      float ai=A[i];
      #pragma unroll
      for(int jo=0;jo<25;jo++) oc[jo]=fmaf(ai,W2u[i*H2+jo],oc[jo]);
    }
    const float* p2u=p2+hfu*25;
    float d=0.f;
    #pragma unroll
    for(int jo=0;jo<25;jo++){ oc[jo]=fmaxf(oc[jo],0.f); d += oc[jo]*p2u[jo]; }
    AGG[SD0 + hf*128 + nG]=d;
  }
  __syncthreads();
  if(tid<K1){
    float nr=0.f;
    #pragma unroll
    for(int i=0;i<H2;i++){ float pv=p2[i]; nr+=pv*pv; }
    float dt=AGG[SD0+tid]+AGG[SD0+128+tid];
    dsc[tid]=tanhf(dt/sqrtf(nr));            // score2
  } else if(tid<NN) dsc[tid]=-3.4e38f;       // pad: excluded by rank predicate
  __syncthreads();
  if(tid<NN){                                 // rank2 (keep flag), vectorized
    float si=dsc[tid]; int r=0;
    #pragma unroll 8
    for(int m4=0;m4<32;m4++){
      float4 v=*(const float4*)&dsc[m4*4];
      int m=m4*4;
      r += (v.x>si)||(v.x==si&&(m  )<tid);
      r += (v.y>si)||(v.y==si&&(m+1)<tid);
      r += (v.z>si)||(v.z==si&&(m+2)<tid);
      r += (v.w>si)||(v.w==si&&(m+3)<tid);
    }
    rmap[tid]=(r<K2)?(signed char)1:(signed char)-1;
  }
  __syncthreads();

  // ================= gated pool via FT column scan (XB/AGG-front dead) =======
  if(nG<K1){
    bool kept=rmap[nG]>0;
    float gv=kept?dsc[nG]:0.f;
    #pragma unroll
    for(int j=0;j<25;j++){
      FT[nG*51 + hfu*25 + j] = kept ? oc[j]*gv : -3.4e38f;
    }
  }
  __syncthreads();
  if(tid<H2){
    float mx=-3.4e38f, sm=0.f;
    for(int n=0;n<K1;n++){
      float v=FT[n*51+tid];
      mx=fmaxf(mx,v);
      sm += (v>-1.0e30f)? v : 0.f;
    }
    AGG[POL+tid]=mx;
    AGG[POL+H2+tid]=sm*(1.0f/(float)K2);
  }
  __syncthreads();

  // ================= fc1 (float4 pol reads) + fc2 =================
  if(tid<FCW){
    float acc=fc1b[tid];
    #pragma unroll
    for(int i4=0;i4<25;i4++){
      float4 pv=*(const float4*)&AGG[POL+i4*4];
      int i=i4*4;
      acc=fmaf(pv.x,fc1W[(i  )*FCW+tid],acc);
      acc=fmaf(pv.y,fc1W[(i+1)*FCW+tid],acc);
      acc=fmaf(pv.z,fc1W[(i+2)*FCW+tid],acc);
      acc=fmaf(pv.w,fc1W[(i+3)*FCW+tid],acc);
    }
    AGG[ZFC+tid]=fmaxf(acc,0.f);
  }
  __syncthreads();
  if(tid<64){
    float a=0.f;
    for(int j=tid;j<FCW;j+=64) a += AGG[ZFC+j]*fc2W[j];
    #pragma unroll
    for(int off=32;off;off>>=1) a += __shfl_down(a,off,64);
    if(tid==0) out[g]=1.0f/(1.0f+expf(-(fc2b[0]+a)));
  }
}

extern "C" void kernel_launch(void* const* d_in, const int* in_sizes, int n_in,
                              void* d_out, int out_size, void* d_ws, size_t ws_size,
                              hipStream_t stream) {
  const float* x    = (const float*)d_in[0];
  const int*   ei   = (const int*)d_in[1];
  // d_in[2] = batch (unused; graphs are equal-size, contiguous)
  const float* W1   = (const float*)d_in[3];
  const float* b1   = (const float*)d_in[4];
  const float* p1   = (const float*)d_in[5];
  const float* W2   = (const float*)d_in[6];
  const float* b2   = (const float*)d_in[7];
  const float* p2   = (const float*)d_in[8];
  const float* fc1W = (const float*)d_in[9];
  const float* fc1b = (const float*)d_in[10];
  const float* fc2W = (const float*)d_in[11];
  const float* fc2b = (const float*)d_in[12];
  float* outp = (float*)d_out;

  gnn_fused<<<BGR, NT, 0, stream>>>(x, ei, W1, b1, p1, W2, b2, p2,
                                    fc1W, fc1b, fc2W, fc2b, outp);
}

// Round 17
// 48.995 us; speedup vs baseline: 1.0261x; 1.0261x over previous
//
#include <hip/hip_runtime.h>
#include <math.h>

constexpr int BGR=1024, NN=128, EG=2048, FIN=30, H1=30, H2=50, K1=103, K2=83, FCW=100;
constexpr int NT=256;
constexpr int EPT=EG/NT;          // 8 packed edges/thread
constexpr int EGP=EG+NN*4;        // padded CSR capacity (deg rounded to x4)
constexpr int SA=36;
constexpr int XBSZ=(NN+1)*32;     // 129 rows; row 128 = zero row (pad sentinel 0x80)
constexpr int AGSZ=NN*SA;         // 4608
// AGG-relative scratch (rows >=104 free: dwords 3744..4607)
constexpr int SD0=3744, POL=4200, ZFC=4304;
// FT: [103][51] gated-value buffer for pool scan; aliases SMEM[0..5252]
// (XB + AGG rows 0..31), all dead after mm2.

// row s, feature i -> dword s*32 + (((i>>2)+s)&7)*4 + (i&3)
__device__ __forceinline__ void row_add4(const float* XB, int s, int cq,
                                         float4&a0, float4&a1, float4&a2, float4&a3){
  int b=s<<5, r=s&7;
  float4 v0=*(const float4*)&XB[b+(((cq  +r)&7)<<2)];
  float4 v1=*(const float4*)&XB[b+(((cq+1+r)&7)<<2)];
  float4 v2=*(const float4*)&XB[b+(((cq+2+r)&7)<<2)];
  float4 v3=*(const float4*)&XB[b+(((cq+3+r)&7)<<2)];
  a0.x+=v0.x; a0.y+=v0.y; a0.z+=v0.z; a0.w+=v0.w;
  a1.x+=v1.x; a1.y+=v1.y; a1.z+=v1.z; a1.w+=v1.w;
  a2.x+=v2.x; a2.y+=v2.y; a2.z+=v2.z; a2.w+=v2.w;
  a3.x+=v3.x; a3.y+=v3.y; a3.z+=v3.z; a3.w+=v3.w;
}

__global__ __launch_bounds__(NT,4) void gnn_fused(
    const float* __restrict__ x, const int* __restrict__ ei,
    const float* __restrict__ W1, const float* __restrict__ b1, const float* __restrict__ p1,
    const float* __restrict__ W2, const float* __restrict__ b2, const float* __restrict__ p2,
    const float* __restrict__ fc1W, const float* __restrict__ fc1b,
    const float* __restrict__ fc2W, const float* __restrict__ fc2b,
    float* __restrict__ out)
{
  const int g=blockIdx.x, tid=threadIdx.x, lane=tid&63, wv=tid>>6;
  const int hf=wv&1;                         // wave-uniform feature half
  const int nG=(tid>>7)*64+lane;             // node: waves{0,1}->0..63, {2,3}->64..127
  const int hfu=__builtin_amdgcn_readfirstlane(hf);
  const int cq=hfu<<2;                       // first of this half's 4 chunks

  __shared__ __align__(16) float SMEM[XBSZ+AGSZ];
  float* XB  = SMEM;
  float* AGG = SMEM+XBSZ;
  float* FT  = SMEM;                          // pool buffer, aliases dead XB/AGG-front
  __shared__ unsigned char eord[EGP];
  __shared__ int cur[NN];
  __shared__ short cstart[NN];
  __shared__ float dsc[NN];                  // dinv1->score1->dinv2->score2
  __shared__ signed char rmap[NN];
  __shared__ int sh_wtot;

  // ---- packed edges + x preloaded into registers ----
  int epk[EPT];
  {
    const int* srcg=ei+(size_t)g*EG;
    const int* dstg=ei+(size_t)BGR*EG+(size_t)g*EG;
    #pragma unroll
    for(int j=0;j<EPT;j++){ int e=tid+j*NT; epk[j]=(srcg[e]&127)|((dstg[e]&127)<<8); }
  }
  float2 xr[8];
  #pragma unroll
  for(int k=0;k<8;k++){
    int l2=tid+k*NT;
    if(l2<NN*15){
      int n=l2/15, i=(l2-n*15)*2;
      xr[k]=*(const float2*)&x[(size_t)g*NN*FIN+n*FIN+i];
    }
  }
  // ---- init: pads, zero row 128, counters ----
  if(tid<NN){ int o=(tid<<5)+(((7+tid)&7)<<2); XB[o+2]=0.f; XB[o+3]=0.f; cur[tid]=0; }
  if(tid>=NN && tid<NN+32) XB[NN*32+(tid-NN)]=0.f;
  __syncthreads();

  // ================= CSR build 1 (pad4, sentinel row 128) =================
  #pragma unroll
  for(int j=0;j<EPT;j++) atomicAdd(&cur[epk[j]>>8],1);
  __syncthreads();
  {
    int mydeg=(tid<NN)?cur[tid]:0;
    int mydeg4=(mydeg+3)&~3;
    int v=mydeg4;
    #pragma unroll
    for(int off=1;off<64;off<<=1){ int t=__shfl_up(v,off,64); if(lane>=off)v+=t; }
    if(tid==63) sh_wtot=v;
    for(int l=tid;l<EGP/4;l+=NT) ((int*)eord)[l]=0x80808080;   // holes -> zero row
    __syncthreads();
    if(tid<NN){
      int start=v-mydeg4+((tid>=64)?sh_wtot:0);
      cur[tid]=start; cstart[tid]=(short)start;
      dsc[tid]=1.0f/sqrtf((float)mydeg+1.0f);                  // dinv1
    }
  }
  __syncthreads();
  // ---- stage x scaled by dinv1 (from regs) + scatter1 (one phase) ----
  #pragma unroll
  for(int k=0;k<8;k++){
    int l2=tid+k*NT;
    if(l2<NN*15){
      int n=l2/15, i=(l2-n*15)*2;
      float di=dsc[n];
      float2 v=xr[k]; v.x*=di; v.y*=di;
      *(float2*)&XB[(n<<5)+((((i>>2)+n)&7)<<2)+(i&3)]=v;
    }
  }
  #pragma unroll
  for(int j=0;j<EPT;j++){ int p=atomicAdd(&cur[epk[j]>>8],1); eord[p]=(unsigned char)(epk[j]&255); }
  __syncthreads();

  // ================= gather1: pure row-sum, final x dinv1 ====================
  {
    float4 a0={0,0,0,0},a1={0,0,0,0},a2={0,0,0,0},a3={0,0,0,0};
    int e0=cstart[nG], deg=cur[nG]-e0;
    int kend=e0+((deg+3)&~3);
    for(int k=e0;k<kend;k+=4){
      uchar4 ss=*(const uchar4*)&eord[k];
      row_add4(XB,ss.x,cq,a0,a1,a2,a3);
      row_add4(XB,ss.y,cq,a0,a1,a2,a3);
      row_add4(XB,ss.z,cq,a0,a1,a2,a3);
      row_add4(XB,ss.w,cq,a0,a1,a2,a3);
    }
    row_add4(XB,nG,cq,a0,a1,a2,a3);          // self: dinv*(... + x'[n])
    float di=dsc[nG];
    a0.x*=di; a0.y*=di; a0.z*=di; a0.w*=di;
    a1.x*=di; a1.y*=di; a1.z*=di; a1.w*=di;
    a2.x*=di; a2.y*=di; a2.z*=di; a2.w*=di;
    a3.x*=di; a3.y*=di; a3.z*=di; a3.w*=di;
    float* dp=&AGG[nG*SA + (hfu<<4)];        // half0 -> feats 0..15, half1 -> 16..29
    ((float4*)dp)[0]=a0; ((float4*)dp)[1]=a1; ((float4*)dp)[2]=a2;
    if(!hfu) ((float4*)dp)[3]=a3;
    else     *(float2*)(dp+12)=make_float2(a3.x,a3.y);
  }
  __syncthreads();                 // x' dead; agg1 ready

  // ================= mm1: scalar-W (wave-uniform) ============================
  float h[15];
  {
    float A[30];
    {
      const float* arow=&AGG[nG*SA];
      float4 t0=((const float4*)arow)[0],t1=((const float4*)arow)[1],t2=((const float4*)arow)[2],
             t3=((const float4*)arow)[3],t4=((const float4*)arow)[4],t5=((const float4*)arow)[5],
             t6=((const float4*)arow)[6];
      float2 t7=*(const float2*)(arow+28);
      A[0]=t0.x;A[1]=t0.y;A[2]=t0.z;A[3]=t0.w; A[4]=t1.x;A[5]=t1.y;A[6]=t1.z;A[7]=t1.w;
      A[8]=t2.x;A[9]=t2.y;A[10]=t2.z;A[11]=t2.w; A[12]=t3.x;A[13]=t3.y;A[14]=t3.z;A[15]=t3.w;
      A[16]=t4.x;A[17]=t4.y;A[18]=t4.z;A[19]=t4.w; A[20]=t5.x;A[21]=t5.y;A[22]=t5.z;A[23]=t5.w;
      A[24]=t6.x;A[25]=t6.y;A[26]=t6.z;A[27]=t6.w; A[28]=t7.x;A[29]=t7.y;
    }
    const float* W1u=W1+hfu*15;
    const float* b1u=b1+hfu*15;
    #pragma unroll
    for(int jo=0;jo<15;jo++) h[jo]=b1u[jo];
    #pragma unroll
    for(int i=0;i<FIN;i++){
      float ai=A[i];
      #pragma unroll
      for(int jo=0;jo<15;jo++) h[jo]=fmaf(ai,W1u[i*H1+jo],h[jo]);
    }
    #pragma unroll
    for(int jo=0;jo<15;jo++) h[jo]=fmaxf(h[jo],0.f);
  }

  // ---- pool1 partial score (per half) ----
  {
    const float* p1u=p1+hfu*15;
    float d=0.f;
    #pragma unroll
    for(int jo=0;jo<15;jo++) d += h[jo]*p1u[jo];
    AGG[SD0 + hf*128 + nG]=d;
  }
  __syncthreads();
  if(tid<NN){
    float nr=0.f;
    #pragma unroll
    for(int i=0;i<H1;i++){ float pv=p1[i]; nr+=pv*pv; }
    float dt=AGG[SD0+tid]+AGG[SD0+128+tid];
    dsc[tid]=tanhf(dt/sqrtf(nr));            // score1
  }
  __syncthreads();
  {  // stable rank (pair-split) == jax.lax.top_k order
    int nR=tid>>1, hR=tid&1;
    float si=dsc[nR];
    int m0=hR<<6, r=0;
    for(int m=m0;m<m0+64;m++){ float sm=dsc[m]; r += (sm>si)||(sm==si&&m<nR); }
    r += __shfl_xor(r,1,64);
    if(!hR) rmap[nR]=(r<K1)?(signed char)r:(signed char)-1;
  }
  __syncthreads();
  {  // gated compact -> swizzled XB rank rows (score only; dinv2 by prescale2)
    int r=rmap[nG];
    if(r>=0){
      float gv=dsc[nG];
      #pragma unroll
      for(int j=0;j<15;j++){
        int i=hfu*15+j;
        XB[(r<<5)+((((i>>2)+r)&7)<<2)+(i&3)]=h[j]*gv;
      }
    }
  }
  #pragma unroll
  for(int j=0;j<EPT;j++){
    int ns=rmap[epk[j]&255], nd=rmap[epk[j]>>8];
    epk[j]=((ns|nd)<0)? -1 : (ns|(nd<<8));
  }
  if(tid<K1) cur[tid]=0;
  __syncthreads();

  // ================= CSR build 2 (pruned, rank ids) =================
  #pragma unroll
  for(int j=0;j<EPT;j++) if(epk[j]>=0) atomicAdd(&cur[epk[j]>>8],1);
  __syncthreads();
  {
    int mydeg=(tid<K1)?cur[tid]:0;
    int mydeg4=(mydeg+3)&~3;
    int v=mydeg4;
    #pragma unroll
    for(int off=1;off<64;off<<=1){ int t=__shfl_up(v,off,64); if(lane>=off)v+=t; }
    if(tid==63) sh_wtot=v;
    for(int l=tid;l<EGP/4;l+=NT) ((int*)eord)[l]=0x80808080;
    __syncthreads();
    if(tid<K1){
      int start=v-mydeg4+((tid>=64)?sh_wtot:0);
      cur[tid]=start; cstart[tid]=(short)start;
      dsc[tid]=1.0f/sqrtf((float)mydeg+1.0f);            // dinv2 (by rank id)
    }
  }
  __syncthreads();
  // ---- scatter2 + prescale2 fused (disjoint targets: eord vs XB rank rows) ----
  #pragma unroll
  for(int j=0;j<EPT;j++) if(epk[j]>=0){ int p=atomicAdd(&cur[epk[j]>>8],1); eord[p]=(unsigned char)(epk[j]&255); }
  if(nG<K1){
    float d2=dsc[nG];
    int b=nG<<5, r=nG&7;
    #pragma unroll
    for(int c=0;c<4;c++){
      float4* q=(float4*)&XB[b+((((cq+c)+r)&7)<<2)];
      float4 v=*q;
      v.x*=d2; v.y*=d2; v.z*=d2; v.w*=d2;
      *q=v;
    }
  }
  __syncthreads();

  // ================= gather2: pure row-sum (pruned CSR), final x dinv2 =======
  if(nG<K1){
    float4 a0={0,0,0,0},a1={0,0,0,0},a2={0,0,0,0},a3={0,0,0,0};
    int e0=cstart[nG], deg=cur[nG]-e0;
    int kend=e0+((deg+3)&~3);
    for(int k=e0;k<kend;k+=4){
      uchar4 ss=*(const uchar4*)&eord[k];
      row_add4(XB,ss.x,cq,a0,a1,a2,a3);
      row_add4(XB,ss.y,cq,a0,a1,a2,a3);
      row_add4(XB,ss.z,cq,a0,a1,a2,a3);
      row_add4(XB,ss.w,cq,a0,a1,a2,a3);
    }
    row_add4(XB,nG,cq,a0,a1,a2,a3);
    float d2=dsc[nG];
    a0.x*=d2; a0.y*=d2; a0.z*=d2; a0.w*=d2;
    a1.x*=d2; a1.y*=d2; a1.z*=d2; a1.w*=d2;
    a2.x*=d2; a2.y*=d2; a2.z*=d2; a2.w*=d2;
    a3.x*=d2; a3.y*=d2; a3.z*=d2; a3.w*=d2;
    float* dp=&AGG[nG*SA + (hfu<<4)];
    ((float4*)dp)[0]=a0; ((float4*)dp)[1]=a1; ((float4*)dp)[2]=a2;
    if(!hfu) ((float4*)dp)[3]=a3;
    else     *(float2*)(dp+12)=make_float2(a3.x,a3.y);
  }
  __syncthreads();                 // agg2 ready

  // ================= mm2: scalar-W + pool2 partial ===========================
  float oc[25];
  if(nG<K1){
    float A[30];
    {
      const float* arow=&AGG[nG*SA];
      float4 t0=((const float4*)arow)[0],t1=((const float4*)arow)[1],t2=((const float4*)arow)[2],
             t3=((const float4*)arow)[3],t4=((const float4*)arow)[4],t5=((const float4*)arow)[5],
             t6=((const float4*)arow)[6];
      float2 t7=*(const float2*)(arow+28);
      A[0]=t0.x;A[1]=t0.y;A[2]=t0.z;A[3]=t0.w; A[4]=t1.x;A[5]=t1.y;A[6]=t1.z;A[7]=t1.w;
      A[8]=t2.x;A[9]=t2.y;A[10]=t2.z;A[11]=t2.w; A[12]=t3.x;A[13]=t3.y;A[14]=t3.z;A[15]=t3.w;
      A[16]=t4.x;A[17]=t4.y;A[18]=t4.z;A[19]=t4.w; A[20]=t5.x;A[21]=t5.y;A[22]=t5.z;A[23]=t5.w;
      A[24]=t6.x;A[25]=t6.y;A[26]=t6.z;A[27]=t6.w; A[28]=t7.x;A[29]=t7.y;
    }
    const float* W2u=W2+hfu*25;
    const float* b2u=b2+hfu*25;
    #pragma unroll
    for(int jo=0;jo<25;jo++) oc[jo]=b2u[jo];
    #pragma unroll
    for(int i=0;i<H1;i++){
      float ai=A[i];
      #pragma unroll
      for(int jo=0;jo<25;jo++) oc[jo]=fmaf(ai,W2u[i*H2+jo],oc[jo]);
    }
    const float* p2u=p2+hfu*25;
    float d=0.f;
    #pragma unroll
    for(int jo=0;jo<25;jo++){ oc[jo]=fmaxf(oc[jo],0.f); d += oc[jo]*p2u[jo]; }
    AGG[SD0 + hf*128 + nG]=d;
  }
  __syncthreads();
  if(tid<K1){
    float nr=0.f;
    #pragma unroll
    for(int i=0;i<H2;i++){ float pv=p2[i]; nr+=pv*pv; }
    float dt=AGG[SD0+tid]+AGG[SD0+128+tid];
    dsc[tid]=tanhf(dt/sqrtf(nr));            // score2
  }
  __syncthreads();
  {  // rank2 (pair-split, keep flag)
    int nR=tid>>1, hR=tid&1;
    float si=(nR<K1)?dsc[nR]:0.f;
    int m0=hR?52:0, m1=hR?K1:52, r=0;
    for(int m=m0;m<m1;m++){ float sm=dsc[m]; r += (sm>si)||(sm==si&&m<nR); }
    r += __shfl_xor(r,1,64);
    if(!hR && nR<K1) rmap[nR]=(r<K2)?(signed char)1:(signed char)-1;
  }
  __syncthreads();

  // ================= gated pool via FT column scan (XB/AGG-front dead) =======
  if(nG<K1){
    bool kept=rmap[nG]>0;
    float gv=kept?dsc[nG]:0.f;
    #pragma unroll
    for(int j=0;j<25;j++){
      FT[nG*51 + hfu*25 + j] = kept ? oc[j]*gv : -3.4e38f;
    }
  }
  __syncthreads();
  if(tid<H2){
    float mx=-3.4e38f, sm=0.f;
    for(int n=0;n<K1;n++){
      float v=FT[n*51+tid];
      mx=fmaxf(mx,v);
      sm += (v>-1.0e30f)? v : 0.f;
    }
    AGG[POL+tid]=mx;
    AGG[POL+H2+tid]=sm*(1.0f/(float)K2);
  }
  __syncthreads();

  // ================= fc1 (float4 pol reads) + fc2 =================
  if(tid<FCW){
    float acc=fc1b[tid];
    #pragma unroll
    for(int i4=0;i4<25;i4++){
      float4 pv=*(const float4*)&AGG[POL+i4*4];
      int i=i4*4;
      acc=fmaf(pv.x,fc1W[(i  )*FCW+tid],acc);
      acc=fmaf(pv.y,fc1W[(i+1)*FCW+tid],acc);
      acc=fmaf(pv.z,fc1W[(i+2)*FCW+tid],acc);
      acc=fmaf(pv.w,fc1W[(i+3)*FCW+tid],acc);
    }
    AGG[ZFC+tid]=fmaxf(acc,0.f);
  }
  __syncthreads();
  if(tid<64){
    float a=0.f;
    for(int j=tid;j<FCW;j+=64) a += AGG[ZFC+j]*fc2W[j];
    #pragma unroll
    for(int off=32;off;off>>=1) a += __shfl_down(a,off,64);
    if(tid==0) out[g]=1.0f/(1.0f+expf(-(fc2b[0]+a)));
  }
}

extern "C" void kernel_launch(void* const* d_in, const int* in_sizes, int n_in,
                              void* d_out, int out_size, void* d_ws, size_t ws_size,
                              hipStream_t stream) {
  const float* x    = (const float*)d_in[0];
  const int*   ei   = (const int*)d_in[1];
  // d_in[2] = batch (unused; graphs are equal-size, contiguous)
  const float* W1   = (const float*)d_in[3];
  const float* b1   = (const float*)d_in[4];
  const float* p1   = (const float*)d_in[5];
  const float* W2   = (const float*)d_in[6];
  const float* b2   = (const float*)d_in[7];
  const float* p2   = (const float*)d_in[8];
  const float* fc1W = (const float*)d_in[9];
  const float* fc1b = (const float*)d_in[10];
  const float* fc2W = (const float*)d_in[11];
  const float* fc2b = (const float*)d_in[12];
  float* outp = (float*)d_out;

  gnn_fused<<<BGR, NT, 0, stream>>>(x, ei, W1, b1, p1, W2, b2, p2,
                                    fc1W, fc1b, fc2W, fc2b, outp);
}